// Round 2
// baseline (3238.631 us; speedup 1.0000x reference)
//
#include <hip/hip_runtime.h>
#include <hip/hip_bf16.h>

#define N_ROWS 32768
#define EMBED  256
#define NCODE  8192
#define BM 64
#define BN 64
#define LDS_PAD 4   // 260-float row stride: 16B-aligned, 2-way (free) bank aliasing

// ---------------------------------------------------------------------------
// Bit-exact emulation of numpy pairwise_sum of x^2 over 256 contiguous fp32.
// numpy: n=256 -> pw(128)+pw(128); each 128-leaf: 8 interleaved accumulators
// r[j] = sum_{k} fl(x[8k+j]^2), combined ((r0+r1)+(r2+r3))+((r4+r5)+(r6+r7)).
// __fmul_rn/__fadd_rn block -ffp-contract=fast FMA fusion (must round mul+add
// separately, like numpy's squared temp array + sum).
// ---------------------------------------------------------------------------
__device__ __forceinline__ float sq_pw128(const float4* p) {
    float r[8];
    float4 a = p[0], b = p[1];
    r[0] = __fmul_rn(a.x, a.x); r[1] = __fmul_rn(a.y, a.y);
    r[2] = __fmul_rn(a.z, a.z); r[3] = __fmul_rn(a.w, a.w);
    r[4] = __fmul_rn(b.x, b.x); r[5] = __fmul_rn(b.y, b.y);
    r[6] = __fmul_rn(b.z, b.z); r[7] = __fmul_rn(b.w, b.w);
    #pragma unroll
    for (int i = 1; i < 16; ++i) {
        a = p[2 * i]; b = p[2 * i + 1];
        r[0] = __fadd_rn(r[0], __fmul_rn(a.x, a.x));
        r[1] = __fadd_rn(r[1], __fmul_rn(a.y, a.y));
        r[2] = __fadd_rn(r[2], __fmul_rn(a.z, a.z));
        r[3] = __fadd_rn(r[3], __fmul_rn(a.w, a.w));
        r[4] = __fadd_rn(r[4], __fmul_rn(b.x, b.x));
        r[5] = __fadd_rn(r[5], __fmul_rn(b.y, b.y));
        r[6] = __fadd_rn(r[6], __fmul_rn(b.z, b.z));
        r[7] = __fadd_rn(r[7], __fmul_rn(b.w, b.w));
    }
    return __fadd_rn(__fadd_rn(__fadd_rn(r[0], r[1]), __fadd_rn(r[2], r[3])),
                     __fadd_rn(__fadd_rn(r[4], r[5]), __fadd_rn(r[6], r[7])));
}

__global__ __launch_bounds__(256) void vq_sqnorm_kernel(const float* __restrict__ x,
                                                        float* __restrict__ out,
                                                        int nrows) {
    int row = blockIdx.x * 256 + threadIdx.x;
    if (row >= nrows) return;
    const float4* p = reinterpret_cast<const float4*>(x + (size_t)row * EMBED);
    out[row] = __fadd_rn(sq_pw128(p), sq_pw128(p + 32));
}

// ---------------------------------------------------------------------------
// main: fused distance + argmin.  d = fl(fl(zn + en) - 2*dot)  (numpy order),
// argmin with lowest-index tie-break (matches np.argmin first-occurrence).
// block = 256 threads (4 waves), owns BM=64 rows, scans codes in BN=64 tiles.
// thread grid 16x16: tx -> 4 codes (strided tx+16j), ty -> 4 rows (4*ty+i).
// ---------------------------------------------------------------------------
__global__ __launch_bounds__(256, 1) void vq_argmin_kernel(const float* __restrict__ z,
                                                           const float* __restrict__ e,
                                                           const float* __restrict__ enorm,
                                                           const float* __restrict__ znorm,
                                                           float* __restrict__ out_idx) {
    __shared__ float zs[BM][EMBED + LDS_PAD];
    __shared__ float es[BN][EMBED + LDS_PAD];
    __shared__ float ns[BN];
    __shared__ float zns[BM];

    const int tid = threadIdx.x;
    const int bm  = blockIdx.x;            // 512 blocks
    const int tx  = tid & 15;
    const int ty  = tid >> 4;

    // stage z tile: 64 rows x 64 float4, coalesced
    {
        const float4* zsrc = reinterpret_cast<const float4*>(z + (size_t)bm * BM * EMBED);
        #pragma unroll
        for (int i = 0; i < 16; ++i) {
            int idx = tid + 256 * i;
            int row = idx >> 6, c4 = idx & 63;
            float4 v = zsrc[row * 64 + c4];
            *reinterpret_cast<float4*>(&zs[row][c4 * 4]) = v;
        }
        if (tid < BM) zns[tid] = znorm[bm * BM + tid];
    }

    float rmin[4];
    int   ridx[4];
    #pragma unroll
    for (int i = 0; i < 4; ++i) { rmin[i] = 3.4e38f; ridx[i] = 0; }

    for (int nt = 0; nt < NCODE / BN; ++nt) {
        // stage e tile
        const float4* esrc = reinterpret_cast<const float4*>(e + (size_t)nt * BN * EMBED);
        #pragma unroll
        for (int i = 0; i < 16; ++i) {
            int idx = tid + 256 * i;
            int row = idx >> 6, c4 = idx & 63;
            float4 v = esrc[row * 64 + c4];
            *reinterpret_cast<float4*>(&es[row][c4 * 4]) = v;
        }
        if (tid < BN) ns[tid] = enorm[nt * BN + tid];
        __syncthreads();   // covers zs/zns on first iter too

        float acc[4][4];
        #pragma unroll
        for (int i = 0; i < 4; ++i)
            #pragma unroll
            for (int j = 0; j < 4; ++j) acc[i][j] = 0.f;

        #pragma unroll 4
        for (int k = 0; k < EMBED; k += 4) {
            float4 a0 = *reinterpret_cast<const float4*>(&zs[ty * 4 + 0][k]);
            float4 a1 = *reinterpret_cast<const float4*>(&zs[ty * 4 + 1][k]);
            float4 a2 = *reinterpret_cast<const float4*>(&zs[ty * 4 + 2][k]);
            float4 a3 = *reinterpret_cast<const float4*>(&zs[ty * 4 + 3][k]);
            float4 b0 = *reinterpret_cast<const float4*>(&es[tx + 0][k]);
            float4 b1 = *reinterpret_cast<const float4*>(&es[tx + 16][k]);
            float4 b2 = *reinterpret_cast<const float4*>(&es[tx + 32][k]);
            float4 b3 = *reinterpret_cast<const float4*>(&es[tx + 48][k]);
            const float4 A[4] = {a0, a1, a2, a3};
            const float4 B[4] = {b0, b1, b2, b3};
            #pragma unroll
            for (int i = 0; i < 4; ++i)
                #pragma unroll
                for (int j = 0; j < 4; ++j) {
                    acc[i][j] += A[i].x * B[j].x;
                    acc[i][j] += A[i].y * B[j].y;
                    acc[i][j] += A[i].z * B[j].z;
                    acc[i][j] += A[i].w * B[j].w;
                }
        }

        // epilogue: d = fl(fl(zn+en) - 2*dot), numpy association; running argmin
        #pragma unroll
        for (int j = 0; j < 4; ++j) {
            int   code = nt * BN + tx + 16 * j;
            float dn   = ns[tx + 16 * j];
            #pragma unroll
            for (int i = 0; i < 4; ++i) {
                float t1 = __fadd_rn(zns[ty * 4 + i], dn);
                float d  = __fsub_rn(t1, 2.0f * acc[i][j]);   // 2*acc exact
                if (d < rmin[i]) { rmin[i] = d; ridx[i] = code; }
            }
        }
        __syncthreads();   // before overwriting es
    }

    // reduce argmin across the 16 column-lanes (tx = lane&15); tie -> smaller index
    #pragma unroll
    for (int m = 1; m < 16; m <<= 1) {
        #pragma unroll
        for (int i = 0; i < 4; ++i) {
            float ov = __shfl_xor(rmin[i], m);
            int   oi = __shfl_xor(ridx[i], m);
            if (ov < rmin[i] || (ov == rmin[i] && oi < ridx[i])) { rmin[i] = ov; ridx[i] = oi; }
        }
    }
    if (tx == 0) {
        #pragma unroll
        for (int i = 0; i < 4; ++i)
            out_idx[bm * BM + ty * 4 + i] = (float)ridx[i];
    }
}

// ---------------- gather: z_q = e[idx] ----------------
__global__ __launch_bounds__(256) void vq_gather_kernel(const float* __restrict__ e,
                                                        const float* __restrict__ idxf,
                                                        float* __restrict__ zq) {
    int row  = blockIdx.x * 4 + (threadIdx.x >> 6);   // one wave per row
    int lane = threadIdx.x & 63;
    int idx  = (int)idxf[row];
    float4 v = reinterpret_cast<const float4*>(e + (size_t)idx * EMBED)[lane];
    reinterpret_cast<float4*>(zq + (size_t)row * EMBED)[lane] = v;
}

extern "C" void kernel_launch(void* const* d_in, const int* in_sizes, int n_in,
                              void* d_out, int out_size, void* d_ws, size_t ws_size,
                              hipStream_t stream) {
    const float* z = (const float*)d_in[0];   // (32,32,32,256) fp32 = 32768x256
    const float* e = (const float*)d_in[1];   // (8192,256) fp32

    float* out     = (float*)d_out;                   // [z_q (8388608) | indices (32768)]
    float* out_idx = out + (size_t)N_ROWS * EMBED;
    float* enorm   = (float*)d_ws;                    // 8192 floats
    float* znorm   = enorm + NCODE;                   // 32768 floats (total 160 KB ws)

    vq_sqnorm_kernel<<<NCODE / 256, 256, 0, stream>>>(e, enorm, NCODE);
    vq_sqnorm_kernel<<<N_ROWS / 256, 256, 0, stream>>>(z, znorm, N_ROWS);
    vq_argmin_kernel<<<N_ROWS / BM, 256, 0, stream>>>(z, e, enorm, znorm, out_idx);
    vq_gather_kernel<<<N_ROWS / 4, 256, 0, stream>>>(e, out_idx, out);
}